// Round 20
// baseline (102.189 us; speedup 1.0000x reference)
//
#include <hip/hip_runtime.h>
#include <math.h>

typedef _Float16 f16;
typedef _Float16 f16x8 __attribute__((ext_vector_type(8)));
typedef float    f32x16 __attribute__((ext_vector_type(16)));
typedef unsigned int uint;
typedef unsigned short u16;

#define B_Q     1024
#define DIM     128
#define N_KEYS  100000
#define NPAD    102400          /* padded to 3200 groups of 32 */
#define NGP     (NPAD / 32)     /* 3200 groups */
#define GPC     8               /* groups per chunk (256 keys) — r14 optimum */
#define NCHUNK  (NGP / GPC)     /* 400 chunks, 50 per XCD */
#define N_CLS   1000
#define QSCALE  11.541560327111707f /* 8/ln2: fold beta*log2(e) into queries */
#define NH      64              /* hist blocks */
#define QGRP    (B_Q / 32)      /* 32 query groups */
#define ZFLOATS ((N_CLS + 2) * B_Q)     /* out_t + dummy sink row + qtot */

// ---- label histogram: per-block COLUMNS (transposed for coalesced scan) ----
__global__ void k_hist(const int* __restrict__ labels, uint* __restrict__ histT) {
    __shared__ uint lh[N_CLS];
    for (int i = threadIdx.x; i < N_CLS; i += blockDim.x) lh[i] = 0;
    __syncthreads();
    const int stride = gridDim.x * blockDim.x;
    for (int i = blockIdx.x * blockDim.x + threadIdx.x; i < N_KEYS; i += stride)
        atomicAdd(&lh[labels[i]], 1u);
    __syncthreads();
    for (int i = threadIdx.x; i < N_CLS; i += blockDim.x)
        histT[i * NH + blockIdx.x] = lh[i];      // class-major: scan reads contig
}

// ---- reduce per-class rows + exclusive scan (shfl-based, 2 barriers) ----
__global__ __launch_bounds__(1024)
void k_scan(const uint* __restrict__ histT, uint* __restrict__ cursor) {
    __shared__ uint wtot[16];
    const int t = threadIdx.x;          // 1024 threads = 16 waves
    const int w = t >> 6, lane = t & 63;
    uint v = 0;
    if (t < N_CLS) {
        const uint4* p = (const uint4*)(histT + t * NH);   // 64 contiguous uints
        #pragma unroll
        for (int b = 0; b < NH / 4; ++b) {
            const uint4 x = p[b];
            v += x.x + x.y + x.z + x.w;
        }
    }
    uint s = v;                          // inclusive wave scan
    #pragma unroll
    for (int o = 1; o < 64; o <<= 1) {
        const uint x = __shfl_up(s, o);
        if (lane >= o) s += x;
    }
    if (lane == 63) wtot[w] = s;
    __syncthreads();
    if (w == 0) {
        uint ws = (lane < 16) ? wtot[lane] : 0;
        #pragma unroll
        for (int o = 1; o < 16; o <<= 1) {
            const uint x = __shfl_up(ws, o);
            if (lane >= o) ws += x;
        }
        if (lane < 16) wtot[lane] = ws;
    }
    __syncthreads();
    const uint prefix = (w > 0) ? wtot[w - 1] : 0;
    if (t < N_CLS) cursor[t] = prefix + s - v;      // exclusive
}

// ---- sort permutation: src[pos] = source key index; dummies src = -1 ----
__global__ void k_perm(const int* __restrict__ labels, uint* __restrict__ cursor,
                       int* __restrict__ src, u16* __restrict__ kcls) {
    const int n = blockIdx.x * blockDim.x + threadIdx.x;
    if (n >= NPAD) return;
    if (n < N_KEYS) {
        const int lab = labels[n];
        const int pos = (int)atomicAdd(&cursor[lab], 1u);
        src[pos]  = n;
        kcls[pos] = (u16)lab;
    } else {
        src[n]  = -1;
        kcls[n] = (u16)N_CLS;
    }
}

// ---- gather-prep (+ fused meta computation + fused zeroing) ----
__global__ __launch_bounds__(256)
void k_gather(const float* __restrict__ qm, const float* __restrict__ km,
              const int* __restrict__ src, const u16* __restrict__ kcls,
              f16* __restrict__ kf2, f16* __restrict__ qf2,
              int* __restrict__ meta, float* __restrict__ zbase) {
    __shared__ float ssq[8][32];
    __shared__ float scale[32];
    const int g = blockIdx.x;            // 0..NGP-1 keys, NGP..NGP+31 queries
    const int t = threadIdx.x;
    const int r = t & 31;
    const int p = t >> 5;
    const bool isq = g >= NGP;

    {   // fused zeroing of out_t + sink + qtot
        const int zi = g * 256 + t;
        if (zi < ZFLOATS / 4)
            ((float4*)zbase)[zi] = float4{0.f, 0.f, 0.f, 0.f};
    }
    if (!isq && t < 64) {                // fused per-group class metadata
        const int  cl = kcls[g * 32 + (t & 31)];
        const int  ca = __shfl(cl, 0);
        const uint dm = (uint)(__ballot(cl != ca) & 0xffffffffull);
        const int  split = dm ? (__ffs(dm) - 1) : 32;
        const int  cb = (split < 32) ? __shfl(cl, split) : ca;
        if (t == 0) meta[g] = ca | (cb << 11) | (split << 22);
    }

    const float* srow;
    if (isq) srow = qm + (size_t)((g - NGP) * 32 + r) * DIM;
    else {
        const int sr = src[g * 32 + r];
        srow = (sr >= 0) ? km + (size_t)sr * DIM : nullptr;
    }

    float4 v[4];
    float ss = 0.0f;
    if (srow) {
        #pragma unroll
        for (int i = 0; i < 4; ++i) {
            v[i] = *(const float4*)(srow + p * 16 + i * 4);
            ss += v[i].x * v[i].x + v[i].y * v[i].y
                + v[i].z * v[i].z + v[i].w * v[i].w;
        }
    } else {
        #pragma unroll
        for (int i = 0; i < 4; ++i) v[i] = float4{0.f, 0.f, 0.f, 0.f};
    }
    ssq[p][r] = ss;
    __syncthreads();
    if (t < 32) {
        float s = 0.0f;
        #pragma unroll
        for (int i = 0; i < 8; ++i) s += ssq[i][t];
        scale[t] = (isq ? QSCALE : 1.0f) / fmaxf(sqrtf(s), 1e-12f);
    }
    __syncthreads();
    const float sc = scale[r];

    const float f[16] = {v[0].x, v[0].y, v[0].z, v[0].w,
                         v[1].x, v[1].y, v[1].z, v[1].w,
                         v[2].x, v[2].y, v[2].z, v[2].w,
                         v[3].x, v[3].y, v[3].z, v[3].w};
    f16x8 h0, h1;
    #pragma unroll
    for (int j = 0; j < 8; ++j) {
        h0[j] = (f16)(f[j]     * sc);
        h1[j] = (f16)(f[j + 8] * sc);
    }
    f16* dst = isq ? qf2 + (size_t)(g - NGP) * 4096
                   : kf2 + (size_t)g * 4096;
    *(f16x8*)(dst + p * 512 +       r * 8) = h0;
    *(f16x8*)(dst + p * 512 + 256 + r * 8) = h1;
}

// ---- main: r14's class_gemm7 verbatim (proven 40.6us optimum: GPC=8,
// 1-wave blocks, no setprio). Swapped-operand MFMA, 2-deep register K
// prefetch, run-merged flush, fused softmax denominator, XCD chunks.
#define FLUSH2(C) {                                                           \
        const float v0 = racc0 + __shfl_xor(racc0, 32);                       \
        const float v1 = racc1 + __shfl_xor(racc1, 32);                       \
        if ((C) != N_CLS) { tot0 += racc0; tot1 += racc1; }                   \
        if (lhi == 0) {                                                       \
            atomicAdd(&out_t[(size_t)(C) * B_Q + q00 + l31], v0);             \
            atomicAdd(&out_t[(size_t)(C) * B_Q + q01 + l31], v1);             \
        }                                                                     \
    }

#define LOADK(DST, I) {                                                       \
        const f16* _kb = kf2 + (size_t)(g0 + (I)) * 4096 + lane * 8;          \
        _Pragma("unroll")                                                     \
        for (int kk = 0; kk < 8; ++kk) DST[kk] = *(const f16x8*)(_kb + kk * 512); \
    }

#define BODY(KB, I) {                                                         \
        const int m     = __shfl(mv, (I));                                    \
        const int ca    = m & 0x7FF;                                          \
        const int cb    = (m >> 11) & 0x7FF;                                  \
        const int split = m >> 22;                                            \
        f32x16 c0 = {}, c1 = {};                                              \
        _Pragma("unroll")                                                     \
        for (int kk = 0; kk < 8; ++kk) {                                      \
            c0 = __builtin_amdgcn_mfma_f32_32x32x16_f16(KB[kk], Q0[kk], c0, 0, 0, 0); \
            c1 = __builtin_amdgcn_mfma_f32_32x32x16_f16(KB[kk], Q1[kk], c1, 0, 0, 0); \
        }                                                                     \
        if (ca != cur) {                                                      \
            if (cur >= 0) FLUSH2(cur);                                        \
            racc0 = 0.0f; racc1 = 0.0f;                                       \
            cur = ca;                                                         \
        }                                                                     \
        if (split == 32) {                                                    \
            float ga = 0.f, gb = 0.f, gc = 0.f, gd = 0.f;                     \
            _Pragma("unroll")                                                 \
            for (int r = 0; r < 16; r += 2) {                                 \
                ga += __builtin_amdgcn_exp2f(c0[r]);                          \
                gb += __builtin_amdgcn_exp2f(c0[r + 1]);                      \
                gc += __builtin_amdgcn_exp2f(c1[r]);                          \
                gd += __builtin_amdgcn_exp2f(c1[r + 1]);                      \
            }                                                                 \
            racc0 += ga + gb;                                                 \
            racc1 += gc + gd;                                                 \
        } else {                                                              \
            float ga = 0.f, gb = 0.f, gc = 0.f, gd = 0.f;                     \
            float ha = 0.f, hb = 0.f, hc = 0.f, hd = 0.f;                     \
            _Pragma("unroll")                                                 \
            for (int r = 0; r < 16; r += 2) {                                 \
                const int  kr0 = ((r & 3) + 8 * (r >> 2)) + lhi4;             \
                const int  kr1 = (((r + 1) & 3) + 8 * ((r + 1) >> 2)) + lhi4; \
                const float e0  = __builtin_amdgcn_exp2f(c0[r]);              \
                const float e0b = __builtin_amdgcn_exp2f(c0[r + 1]);          \
                const float e1  = __builtin_amdgcn_exp2f(c1[r]);              \
                const float e1b = __builtin_amdgcn_exp2f(c1[r + 1]);          \
                const bool inA0 = kr0 < split;                                \
                const bool inA1 = kr1 < split;                                \
                ga += inA0 ? e0  : 0.0f;  ha += inA0 ? 0.0f : e0;             \
                gb += inA1 ? e0b : 0.0f;  hb += inA1 ? 0.0f : e0b;            \
                gc += inA0 ? e1  : 0.0f;  hc += inA0 ? 0.0f : e1;             \
                gd += inA1 ? e1b : 0.0f;  hd += inA1 ? 0.0f : e1b;            \
            }                                                                 \
            racc0 += ga + gb;                                                 \
            racc1 += gc + gd;                                                 \
            FLUSH2(cur);                                                      \
            racc0 = ha + hb;                                                  \
            racc1 = hc + hd;                                                  \
            cur = cb;                                                         \
        }                                                                     \
    }

__global__ __launch_bounds__(64)
void class_gemm13(const f16* __restrict__ kf2, const f16* __restrict__ qf2,
                  const int* __restrict__ meta, float* __restrict__ out_t,
                  float* __restrict__ qtot) {
    const int lane = threadIdx.x & 63;
    const int l31  = lane & 31;
    const int lhi  = lane >> 5;
    const int lhi4 = lhi << 2;

    // 1 wave = (chunk, qquad, wsub); 16 sibling waves of a chunk share b&7
    const int b     = blockIdx.x;           // 0..6399
    const int xcd   = b & 7;
    const int u     = b >> 3;               // 0..799
    const int chunk = xcd * (NCHUNK / 8) + (u >> 4);
    const int qquad = (u >> 2) & 3;
    const int wsub  = u & 3;
    const int g0    = chunk * GPC;

    f16x8 Q0[8], Q1[8];
    {
        const f16* qa = qf2 + (size_t)(qquad * 8 + wsub * 2) * 4096 + lane * 8;
        #pragma unroll
        for (int kk = 0; kk < 8; ++kk) {
            Q0[kk] = *(const f16x8*)(qa + kk * 512);
            Q1[kk] = *(const f16x8*)(qa + 4096 + kk * 512);
        }
    }
    const int q00 = qquad * 256 + wsub * 64;
    const int q01 = q00 + 32;

    const int mv = meta[g0 + (lane & (GPC - 1))];

    float racc0 = 0.0f, racc1 = 0.0f;
    float tot0  = 0.0f, tot1  = 0.0f;
    int cur = -1;

    f16x8 K0[8], K1[8];
    LOADK(K0, 0);
    #pragma unroll 1                         // rolled: r14-proven skeleton
    for (int ii = 0; ii < GPC / 2; ++ii) {
        const int i0 = 2 * ii, i1 = 2 * ii + 1;
        LOADK(K1, i1);
        BODY(K0, i0);
        if (ii + 1 < GPC / 2) LOADK(K0, i1 + 1);
        BODY(K1, i1);
    }
    if (cur >= 0) FLUSH2(cur);

    {   // fused softmax denominator
        const float t0 = tot0 + __shfl_xor(tot0, 32);
        const float t1 = tot1 + __shfl_xor(tot1, 32);
        if (lhi == 0) {
            atomicAdd(&qtot[q00 + l31], t0);
            atomicAdd(&qtot[q01 + l31], t1);
        }
    }
}

// ---- epilogue: 64x64 scaled transpose tiles; denominator from qtot ----
__global__ __launch_bounds__(256)
void k_norm_t(const float* __restrict__ out_t, const float* __restrict__ qtot,
              float* __restrict__ out) {
    __shared__ float tile[64 * 65];
    __shared__ float invq[64];
    const int tid  = threadIdx.x;
    const int w    = tid >> 6;
    const int lane = tid & 63;
    const int q0   = blockIdx.x * 64;
    const int c0   = blockIdx.y * 64;

    if (tid < 64) invq[tid] = 1.0f / qtot[q0 + tid];

    #pragma unroll
    for (int i = 0; i < 16; ++i) {
        const int cidx = c0 + w * 16 + i;
        const float v = (cidx < N_CLS) ? out_t[(size_t)cidx * B_Q + q0 + lane] : 0.0f;
        tile[lane * 65 + w * 16 + i] = v;
    }
    __syncthreads();
    #pragma unroll
    for (int j = 0; j < 16; ++j) {
        const int r    = w * 16 + j;
        const int cidx = c0 + lane;
        if (cidx < N_CLS)
            out[(size_t)(q0 + r) * N_CLS + cidx] = tile[r * 65 + lane] * invq[r];
    }
}

extern "C" void kernel_launch(void* const* d_in, const int* in_sizes, int n_in,
                              void* d_out, int out_size, void* d_ws, size_t ws_size,
                              hipStream_t stream) {
    const float* qm     = (const float*)d_in[0];
    const float* km     = (const float*)d_in[1];
    const int*   labels = (const int*)d_in[2];
    float* out = (float*)d_out;

    char* p = (char*)d_ws;
    f16*   kf2     = (f16*)p;   p += (size_t)NPAD * DIM * 2;        // 26.2 MB
    f16*   qf2     = (f16*)p;   p += (size_t)B_Q * DIM * 2;         // 256 KB
    float* out_t   = (float*)p; p += (size_t)N_CLS * B_Q * 4;       // 4.1 MB
    float* sink    = (float*)p; p += (size_t)B_Q * 4;               // dummy row 1000
    float* qtot    = (float*)p; p += (size_t)B_Q * 4;               // 4 KB
    uint*  cursor  = (uint*)p;  p += N_CLS * 4;
    u16*   kcls    = (u16*)p;   p += (size_t)NPAD * 2;              // 205 KB
    int*   meta    = (int*)p;   p += (size_t)NGP * 4;               // 12.8 KB
    int*   src     = (int*)p;   p += (size_t)NPAD * 4;              // 410 KB
    (void)sink;
    uint*  histT   = (uint*)out_t;       // aliases out_t; consumed before zeroing

    hipLaunchKernelGGL(k_hist, dim3(NH), dim3(256), 0, stream, labels, histT);
    hipLaunchKernelGGL(k_scan, dim3(1), dim3(1024), 0, stream, histT, cursor);
    hipLaunchKernelGGL(k_perm, dim3(NPAD / 256), dim3(256), 0, stream,
                       labels, cursor, src, kcls);
    hipLaunchKernelGGL(k_gather, dim3(NGP + QGRP), dim3(256), 0, stream,
                       qm, km, src, kcls, kf2, qf2, meta, out_t);

    hipLaunchKernelGGL(class_gemm13, dim3(16 * NCHUNK), dim3(64), 0, stream,
                       kf2, qf2, meta, out_t, qtot);

    hipLaunchKernelGGL(k_norm_t, dim3(B_Q / 64, (N_CLS + 63) / 64), dim3(256), 0, stream,
                       out_t, qtot, out);
}

// Round 21
// 95.576 us; speedup vs baseline: 1.0692x; 1.0692x over previous
//
#include <hip/hip_runtime.h>
#include <math.h>

typedef _Float16 f16;
typedef _Float16 f16x8 __attribute__((ext_vector_type(8)));
typedef float    f32x16 __attribute__((ext_vector_type(16)));
typedef unsigned int uint;
typedef unsigned short u16;

#define B_Q     1024
#define DIM     128
#define N_KEYS  100000
#define NPAD    102400          /* padded to 3200 groups of 32 */
#define NGP     (NPAD / 32)     /* 3200 groups */
#define GPC     8               /* groups per chunk (256 keys) — r14 optimum */
#define NCHUNK  (NGP / GPC)     /* 400 chunks, 50 per XCD */
#define N_CLS   1000
#define QSCALE  11.541560327111707f /* 8/ln2: fold beta*log2(e) into queries */
#define NH      64              /* hist blocks */
#define QGRP    (B_Q / 32)      /* 32 query groups */
#define ZFLOATS ((N_CLS + 2) * B_Q)     /* out_t + dummy sink row + qtot */

// ---- label histogram: per-block rows, no global atomics ----
__global__ void k_hist(const int* __restrict__ labels, uint* __restrict__ histNB) {
    __shared__ uint lh[N_CLS];
    for (int i = threadIdx.x; i < N_CLS; i += blockDim.x) lh[i] = 0;
    __syncthreads();
    const int stride = gridDim.x * blockDim.x;
    for (int i = blockIdx.x * blockDim.x + threadIdx.x; i < N_KEYS; i += stride)
        atomicAdd(&lh[labels[i]], 1u);
    __syncthreads();
    for (int i = threadIdx.x; i < N_CLS; i += blockDim.x)
        histNB[blockIdx.x * N_CLS + i] = lh[i];
}

// ---- reduce per-block hists + exclusive scan (shfl-based, 2 barriers) ----
__global__ __launch_bounds__(1024)
void k_scan(const uint* __restrict__ histNB, uint* __restrict__ cursor) {
    __shared__ uint wtot[16];
    const int t = threadIdx.x;          // 1024 threads = 16 waves
    const int w = t >> 6, lane = t & 63;
    uint v = 0;
    if (t < N_CLS)
        for (int b = 0; b < NH; ++b) v += histNB[b * N_CLS + t];
    uint s = v;                          // inclusive wave scan
    #pragma unroll
    for (int o = 1; o < 64; o <<= 1) {
        const uint x = __shfl_up(s, o);
        if (lane >= o) s += x;
    }
    if (lane == 63) wtot[w] = s;
    __syncthreads();
    if (w == 0) {
        uint ws = (lane < 16) ? wtot[lane] : 0;
        #pragma unroll
        for (int o = 1; o < 16; o <<= 1) {
            const uint x = __shfl_up(ws, o);
            if (lane >= o) ws += x;
        }
        if (lane < 16) wtot[lane] = ws;
    }
    __syncthreads();
    const uint prefix = (w > 0) ? wtot[w - 1] : 0;
    if (t < N_CLS) cursor[t] = prefix + s - v;      // exclusive
}

// ---- sort permutation: src[pos] = source key index; dummies src = -1 ----
__global__ void k_perm(const int* __restrict__ labels, uint* __restrict__ cursor,
                       int* __restrict__ src, u16* __restrict__ kcls) {
    const int n = blockIdx.x * blockDim.x + threadIdx.x;
    if (n >= NPAD) return;
    if (n < N_KEYS) {
        const int lab = labels[n];
        const int pos = (int)atomicAdd(&cursor[lab], 1u);
        src[pos]  = n;
        kcls[pos] = (u16)lab;
    } else {
        src[n]  = -1;
        kcls[n] = (u16)N_CLS;
    }
}

// ---- gather-prep (+ fused meta computation + fused zeroing) ----
__global__ __launch_bounds__(256)
void k_gather(const float* __restrict__ qm, const float* __restrict__ km,
              const int* __restrict__ src, const u16* __restrict__ kcls,
              f16* __restrict__ kf2, f16* __restrict__ qf2,
              int* __restrict__ meta, float* __restrict__ zbase) {
    __shared__ float ssq[8][32];
    __shared__ float scale[32];
    const int g = blockIdx.x;            // 0..NGP-1 keys, NGP..NGP+31 queries
    const int t = threadIdx.x;
    const int r = t & 31;
    const int p = t >> 5;
    const bool isq = g >= NGP;

    {   // fused zeroing of out_t + sink + qtot
        const int zi = g * 256 + t;
        if (zi < ZFLOATS / 4)
            ((float4*)zbase)[zi] = float4{0.f, 0.f, 0.f, 0.f};
    }
    if (!isq && t < 64) {                // fused per-group class metadata
        const int  cl = kcls[g * 32 + (t & 31)];
        const int  ca = __shfl(cl, 0);
        const uint dm = (uint)(__ballot(cl != ca) & 0xffffffffull);
        const int  split = dm ? (__ffs(dm) - 1) : 32;
        const int  cb = (split < 32) ? __shfl(cl, split) : ca;
        if (t == 0) meta[g] = ca | (cb << 11) | (split << 22);
    }

    const float* srow;
    if (isq) srow = qm + (size_t)((g - NGP) * 32 + r) * DIM;
    else {
        const int sr = src[g * 32 + r];
        srow = (sr >= 0) ? km + (size_t)sr * DIM : nullptr;
    }

    float4 v[4];
    float ss = 0.0f;
    if (srow) {
        #pragma unroll
        for (int i = 0; i < 4; ++i) {
            v[i] = *(const float4*)(srow + p * 16 + i * 4);
            ss += v[i].x * v[i].x + v[i].y * v[i].y
                + v[i].z * v[i].z + v[i].w * v[i].w;
        }
    } else {
        #pragma unroll
        for (int i = 0; i < 4; ++i) v[i] = float4{0.f, 0.f, 0.f, 0.f};
    }
    ssq[p][r] = ss;
    __syncthreads();
    if (t < 32) {
        float s = 0.0f;
        #pragma unroll
        for (int i = 0; i < 8; ++i) s += ssq[i][t];
        scale[t] = (isq ? QSCALE : 1.0f) / fmaxf(sqrtf(s), 1e-12f);
    }
    __syncthreads();
    const float sc = scale[r];

    const float f[16] = {v[0].x, v[0].y, v[0].z, v[0].w,
                         v[1].x, v[1].y, v[1].z, v[1].w,
                         v[2].x, v[2].y, v[2].z, v[2].w,
                         v[3].x, v[3].y, v[3].z, v[3].w};
    f16x8 h0, h1;
    #pragma unroll
    for (int j = 0; j < 8; ++j) {
        h0[j] = (f16)(f[j]     * sc);
        h1[j] = (f16)(f[j + 8] * sc);
    }
    f16* dst = isq ? qf2 + (size_t)(g - NGP) * 4096
                   : kf2 + (size_t)g * 4096;
    *(f16x8*)(dst + p * 512 +       r * 8) = h0;
    *(f16x8*)(dst + p * 512 + 256 + r * 8) = h1;
}

// ---- main: r14's class_gemm7 byte-exact — FULL unroll (104 VGPR, 40.6us;
// the rolled "#pragma unroll 1" variant of r15-r20 compiles to 120 VGPR and
// costs ~2us). 1-wave blocks, swapped-operand MFMA, 2-deep register K
// prefetch, run-merged flush, fused softmax denominator, XCD chunks.
#define FLUSH2(C) {                                                           \
        const float v0 = racc0 + __shfl_xor(racc0, 32);                       \
        const float v1 = racc1 + __shfl_xor(racc1, 32);                       \
        if ((C) != N_CLS) { tot0 += racc0; tot1 += racc1; }                   \
        if (lhi == 0) {                                                       \
            atomicAdd(&out_t[(size_t)(C) * B_Q + q00 + l31], v0);             \
            atomicAdd(&out_t[(size_t)(C) * B_Q + q01 + l31], v1);             \
        }                                                                     \
    }

#define LOADK(DST, I) {                                                       \
        const f16* _kb = kf2 + (size_t)(g0 + (I)) * 4096 + lane * 8;          \
        _Pragma("unroll")                                                     \
        for (int kk = 0; kk < 8; ++kk) DST[kk] = *(const f16x8*)(_kb + kk * 512); \
    }

#define BODY(KB, I) {                                                         \
        const int m     = __shfl(mv, (I));      /* static lane -> readlane */ \
        const int ca    = m & 0x7FF;                                          \
        const int cb    = (m >> 11) & 0x7FF;                                  \
        const int split = m >> 22;                                            \
        f32x16 c0 = {}, c1 = {};                                              \
        _Pragma("unroll")                                                     \
        for (int kk = 0; kk < 8; ++kk) {                                      \
            c0 = __builtin_amdgcn_mfma_f32_32x32x16_f16(KB[kk], Q0[kk], c0, 0, 0, 0); \
            c1 = __builtin_amdgcn_mfma_f32_32x32x16_f16(KB[kk], Q1[kk], c1, 0, 0, 0); \
        }                                                                     \
        if (ca != cur) {                                                      \
            if (cur >= 0) FLUSH2(cur);                                        \
            racc0 = 0.0f; racc1 = 0.0f;                                       \
            cur = ca;                                                         \
        }                                                                     \
        if (split == 32) {                                                    \
            float ga = 0.f, gb = 0.f, gc = 0.f, gd = 0.f;                     \
            _Pragma("unroll")                                                 \
            for (int r = 0; r < 16; r += 2) {                                 \
                ga += __builtin_amdgcn_exp2f(c0[r]);                          \
                gb += __builtin_amdgcn_exp2f(c0[r + 1]);                      \
                gc += __builtin_amdgcn_exp2f(c1[r]);                          \
                gd += __builtin_amdgcn_exp2f(c1[r + 1]);                      \
            }                                                                 \
            racc0 += ga + gb;                                                 \
            racc1 += gc + gd;                                                 \
        } else {                                                              \
            float ga = 0.f, gb = 0.f, gc = 0.f, gd = 0.f;                     \
            float ha = 0.f, hb = 0.f, hc = 0.f, hd = 0.f;                     \
            _Pragma("unroll")                                                 \
            for (int r = 0; r < 16; r += 2) {                                 \
                const int  kr0 = ((r & 3) + 8 * (r >> 2)) + lhi4;             \
                const int  kr1 = (((r + 1) & 3) + 8 * ((r + 1) >> 2)) + lhi4; \
                const float e0  = __builtin_amdgcn_exp2f(c0[r]);              \
                const float e0b = __builtin_amdgcn_exp2f(c0[r + 1]);          \
                const float e1  = __builtin_amdgcn_exp2f(c1[r]);              \
                const float e1b = __builtin_amdgcn_exp2f(c1[r + 1]);          \
                const bool inA0 = kr0 < split;                                \
                const bool inA1 = kr1 < split;                                \
                ga += inA0 ? e0  : 0.0f;  ha += inA0 ? 0.0f : e0;             \
                gb += inA1 ? e0b : 0.0f;  hb += inA1 ? 0.0f : e0b;            \
                gc += inA0 ? e1  : 0.0f;  hc += inA0 ? 0.0f : e1;             \
                gd += inA1 ? e1b : 0.0f;  hd += inA1 ? 0.0f : e1b;            \
            }                                                                 \
            racc0 += ga + gb;                                                 \
            racc1 += gc + gd;                                                 \
            FLUSH2(cur);                                                      \
            racc0 = ha + hb;                                                  \
            racc1 = hc + hd;                                                  \
            cur = cb;                                                         \
        }                                                                     \
    }

__global__ __launch_bounds__(64)
void class_gemm14(const f16* __restrict__ kf2, const f16* __restrict__ qf2,
                  const int* __restrict__ meta, float* __restrict__ out_t,
                  float* __restrict__ qtot) {
    const int lane = threadIdx.x & 63;
    const int l31  = lane & 31;
    const int lhi  = lane >> 5;
    const int lhi4 = lhi << 2;

    // 1 wave = (chunk, qquad, wsub); 16 sibling waves of a chunk share b&7
    const int b     = blockIdx.x;           // 0..6399
    const int xcd   = b & 7;
    const int u     = b >> 3;               // 0..799
    const int chunk = xcd * (NCHUNK / 8) + (u >> 4);
    const int qquad = (u >> 2) & 3;
    const int wsub  = u & 3;
    const int g0    = chunk * GPC;

    f16x8 Q0[8], Q1[8];
    {
        const f16* qa = qf2 + (size_t)(qquad * 8 + wsub * 2) * 4096 + lane * 8;
        #pragma unroll
        for (int kk = 0; kk < 8; ++kk) {
            Q0[kk] = *(const f16x8*)(qa + kk * 512);
            Q1[kk] = *(const f16x8*)(qa + 4096 + kk * 512);
        }
    }
    const int q00 = qquad * 256 + wsub * 64;
    const int q01 = q00 + 32;

    const int mv = meta[g0 + (lane & (GPC - 1))];

    float racc0 = 0.0f, racc1 = 0.0f;
    float tot0  = 0.0f, tot1  = 0.0f;
    int cur = -1;

    f16x8 K0[8], K1[8];
    LOADK(K0, 0);
    #pragma unroll                           // FULL unroll — r14-proven
    for (int ii = 0; ii < GPC / 2; ++ii) {
        { const int i = 2 * ii;     if (i + 1 < GPC) LOADK(K1, i + 1); BODY(K0, i); }
        { const int i = 2 * ii + 1; if (i + 1 < GPC) LOADK(K0, i + 1); BODY(K1, i); }
    }
    if (cur >= 0) FLUSH2(cur);

    {   // fused softmax denominator
        const float t0 = tot0 + __shfl_xor(tot0, 32);
        const float t1 = tot1 + __shfl_xor(tot1, 32);
        if (lhi == 0) {
            atomicAdd(&qtot[q00 + l31], t0);
            atomicAdd(&qtot[q01 + l31], t1);
        }
    }
}

// ---- epilogue: 64x64 scaled transpose tiles; denominator from qtot ----
__global__ __launch_bounds__(256)
void k_norm_t(const float* __restrict__ out_t, const float* __restrict__ qtot,
              float* __restrict__ out) {
    __shared__ float tile[64 * 65];
    __shared__ float invq[64];
    const int tid  = threadIdx.x;
    const int w    = tid >> 6;
    const int lane = tid & 63;
    const int q0   = blockIdx.x * 64;
    const int c0   = blockIdx.y * 64;

    if (tid < 64) invq[tid] = 1.0f / qtot[q0 + tid];

    #pragma unroll
    for (int i = 0; i < 16; ++i) {
        const int cidx = c0 + w * 16 + i;
        const float v = (cidx < N_CLS) ? out_t[(size_t)cidx * B_Q + q0 + lane] : 0.0f;
        tile[lane * 65 + w * 16 + i] = v;
    }
    __syncthreads();
    #pragma unroll
    for (int j = 0; j < 16; ++j) {
        const int r    = w * 16 + j;
        const int cidx = c0 + lane;
        if (cidx < N_CLS)
            out[(size_t)(q0 + r) * N_CLS + cidx] = tile[r * 65 + lane] * invq[r];
    }
}

extern "C" void kernel_launch(void* const* d_in, const int* in_sizes, int n_in,
                              void* d_out, int out_size, void* d_ws, size_t ws_size,
                              hipStream_t stream) {
    const float* qm     = (const float*)d_in[0];
    const float* km     = (const float*)d_in[1];
    const int*   labels = (const int*)d_in[2];
    float* out = (float*)d_out;

    char* p = (char*)d_ws;
    f16*   kf2     = (f16*)p;   p += (size_t)NPAD * DIM * 2;        // 26.2 MB
    f16*   qf2     = (f16*)p;   p += (size_t)B_Q * DIM * 2;         // 256 KB
    float* out_t   = (float*)p; p += (size_t)N_CLS * B_Q * 4;       // 4.1 MB
    float* sink    = (float*)p; p += (size_t)B_Q * 4;               // dummy row 1000
    float* qtot    = (float*)p; p += (size_t)B_Q * 4;               // 4 KB
    uint*  cursor  = (uint*)p;  p += N_CLS * 4;
    u16*   kcls    = (u16*)p;   p += (size_t)NPAD * 2;              // 205 KB
    int*   meta    = (int*)p;   p += (size_t)NGP * 4;               // 12.8 KB
    int*   src     = (int*)p;   p += (size_t)NPAD * 4;              // 410 KB
    (void)sink;
    uint*  histNB  = (uint*)out_t;       // aliases out_t; consumed before zeroing

    hipLaunchKernelGGL(k_hist, dim3(NH), dim3(256), 0, stream, labels, histNB);
    hipLaunchKernelGGL(k_scan, dim3(1), dim3(1024), 0, stream, histNB, cursor);
    hipLaunchKernelGGL(k_perm, dim3(NPAD / 256), dim3(256), 0, stream,
                       labels, cursor, src, kcls);
    hipLaunchKernelGGL(k_gather, dim3(NGP + QGRP), dim3(256), 0, stream,
                       qm, km, src, kcls, kf2, qf2, meta, out_t);

    hipLaunchKernelGGL(class_gemm14, dim3(16 * NCHUNK), dim3(64), 0, stream,
                       kf2, qf2, meta, out_t, qtot);

    hipLaunchKernelGGL(k_norm_t, dim3(B_Q / 64, (N_CLS + 63) / 64), dim3(256), 0, stream,
                       out_t, qtot, out);
}